// Round 6
// baseline (97.995 us; speedup 1.0000x reference)
//
#include <hip/hip_runtime.h>

#define NY_ 496
#define NX_ 432
#define C_  64
#define PLANE_ (NY_ * NX_)   // 214272

typedef float          f32x4 __attribute__((ext_vector_type(4)));
typedef unsigned short u16x4 __attribute__((ext_vector_type(4)));

// ---------------------------------------------------------------------------
// u16 map scheme: map[cell] = sample-local pillar index (0xFFFF = empty).
// Global pillar = b * PPS + local, where b = cell / PLANE_ is implied by
// position. Init via hipMemsetAsync(0xFF) at streaming fill rate.
// ---------------------------------------------------------------------------

// Pass 2: scatter sample-local pillar index (tiny: P 2-byte writes)
__global__ void scatter_idx16_kernel(const int* __restrict__ coords,
                                     unsigned short* __restrict__ idx,
                                     int P, int PPS) {
    int p = blockIdx.x * blockDim.x + threadIdx.x;
    if (p >= P) return;
    int4 c = reinterpret_cast<const int4*>(coords)[p];
    int lin = c.x * PLANE_ + c.z * NX_ + c.w;
    idx[lin] = (unsigned short)(p - c.x * PPS);
}

// ---------------------------------------------------------------------------
// Pass 3: canvas sweep. Each thread owns TWO quads of 4 consecutive cells:
// q0 = blockIdx*512 + tid, q1 = q0 + 256. A 256-thread block therefore writes
// 8 KiB contiguous per c-plane (two perfectly lane-contiguous 4 KiB bursts),
// doubling the DRAM run length vs one-quad threads. Branchless: empty cells
// gather feats row 0 and multiply by 0.
// ---------------------------------------------------------------------------
__global__ void fill_out8_kernel(const float* __restrict__ feats,
                                 const unsigned short* __restrict__ idx,
                                 float* __restrict__ out, int nquad, int PPS) {
    int q0 = blockIdx.x * (2 * blockDim.x) + threadIdx.x;
    int q1 = q0 + blockDim.x;
    if (q1 >= nquad) {               // tail guard (never taken for exact grids)
        if (q0 >= nquad) return;
        q1 = q0;                     // degenerate: write same quad twice (safe)
    }

    u16x4 l0 = *reinterpret_cast<const u16x4*>(idx + 4 * q0);
    u16x4 l1 = *reinterpret_cast<const u16x4*>(idx + 4 * q1);

    int cell0 = q0 << 2, cell1 = q1 << 2;
    int b0 = cell0 / PLANE_, b1 = cell1 / PLANE_;
    int rem0 = cell0 - b0 * PLANE_, rem1 = cell1 - b1 * PLANE_;
    int base0 = b0 * (C_ * PLANE_) + rem0;
    int base1 = b1 * (C_ * PLANE_) + rem1;
    int pb0 = b0 * PPS, pb1 = b1 * PPS;

    const f32x4* f[8];
    float m[8];
    {
        int li[8] = {l0.x, l0.y, l0.z, l0.w, l1.x, l1.y, l1.z, l1.w};
        int pb[8] = {pb0, pb0, pb0, pb0, pb1, pb1, pb1, pb1};
        #pragma unroll
        for (int i = 0; i < 8; ++i) {
            bool e = (li[i] == 0xFFFF);
            f[i] = reinterpret_cast<const f32x4*>(
                feats + (e ? 0 : ((pb[i] + li[i]) * C_)));
            m[i] = e ? 0.f : 1.f;
        }
    }

    #pragma unroll 4
    for (int cg = 0; cg < C_ / 4; ++cg) {
        f32x4 a0 = f[0][cg] * m[0];
        f32x4 a1 = f[1][cg] * m[1];
        f32x4 a2 = f[2][cg] * m[2];
        f32x4 a3 = f[3][cg] * m[3];
        f32x4 a4 = f[4][cg] * m[4];
        f32x4 a5 = f[5][cg] * m[5];
        f32x4 a6 = f[6][cg] * m[6];
        f32x4 a7 = f[7][cg] * m[7];

        float* o0 = out + base0 + (cg * 4) * PLANE_;
        float* o1 = out + base1 + (cg * 4) * PLANE_;
        f32x4 s;
        s = (f32x4){a0.x, a1.x, a2.x, a3.x};
        __builtin_nontemporal_store(s, reinterpret_cast<f32x4*>(o0));
        s = (f32x4){a4.x, a5.x, a6.x, a7.x};
        __builtin_nontemporal_store(s, reinterpret_cast<f32x4*>(o1));
        s = (f32x4){a0.y, a1.y, a2.y, a3.y};
        __builtin_nontemporal_store(s, reinterpret_cast<f32x4*>(o0 + PLANE_));
        s = (f32x4){a4.y, a5.y, a6.y, a7.y};
        __builtin_nontemporal_store(s, reinterpret_cast<f32x4*>(o1 + PLANE_));
        s = (f32x4){a0.z, a1.z, a2.z, a3.z};
        __builtin_nontemporal_store(s, reinterpret_cast<f32x4*>(o0 + 2 * PLANE_));
        s = (f32x4){a4.z, a5.z, a6.z, a7.z};
        __builtin_nontemporal_store(s, reinterpret_cast<f32x4*>(o1 + 2 * PLANE_));
        s = (f32x4){a0.w, a1.w, a2.w, a3.w};
        __builtin_nontemporal_store(s, reinterpret_cast<f32x4*>(o0 + 3 * PLANE_));
        s = (f32x4){a4.w, a5.w, a6.w, a7.w};
        __builtin_nontemporal_store(s, reinterpret_cast<f32x4*>(o1 + 3 * PLANE_));
    }
}

// ---------------------------------------------------------------------------
// Fallback (ws too small or PPS scheme inapplicable): zero + direct scatter.
// ---------------------------------------------------------------------------
__global__ void zero_out_kernel(float* __restrict__ out, int n4) {
    int t = blockIdx.x * blockDim.x + threadIdx.x;
    int stride = gridDim.x * blockDim.x;
    const float4 z = make_float4(0.f, 0.f, 0.f, 0.f);
    for (int i = t; i < n4; i += stride) {
        reinterpret_cast<float4*>(out)[i] = z;
    }
}

__global__ void direct_scatter_kernel(const float* __restrict__ feats,
                                      const int* __restrict__ coords,
                                      float* __restrict__ out, int P) {
    int p = blockIdx.x * (blockDim.x / 64) + (threadIdx.x >> 6);
    int c = threadIdx.x & 63;
    if (p >= P) return;
    int4 co = reinterpret_cast<const int4*>(coords)[p];
    int pos = co.z * NX_ + co.w;
    out[co.x * (C_ * PLANE_) + c * PLANE_ + pos] = feats[p * C_ + c];
}

extern "C" void kernel_launch(void* const* d_in, const int* in_sizes, int n_in,
                              void* d_out, int out_size, void* d_ws, size_t ws_size,
                              hipStream_t stream) {
    const float* feats  = (const float*)d_in[0];
    const int*   coords = (const int*)d_in[1];
    float* out = (float*)d_out;

    const int P = in_sizes[0] / C_;                 // 96000
    const int B = out_size / (C_ * PLANE_);         // 8
    const int ncells = B * PLANE_;                  // 1,714,176
    const int PPS = (B > 0) ? (P / B) : 0;          // 12000
    const size_t ws_needed = (size_t)ncells * sizeof(unsigned short);

    const bool u16_ok = (B > 0) && (P % B == 0) && (PPS < 0xFFFF) &&
                        (ws_size >= ws_needed);

    if (u16_ok) {
        unsigned short* idx = (unsigned short*)d_ws;
        const int nquad = ncells / 4;               // 428,544
        hipMemsetAsync(idx, 0xFF, ws_needed, stream);
        {
            int blocks = (P + 255) / 256;
            scatter_idx16_kernel<<<blocks, 256, 0, stream>>>(coords, idx, P, PPS);
        }
        {
            int blocks = (nquad + 511) / 512;       // 837, 2 quads/thread
            fill_out8_kernel<<<blocks, 256, 0, stream>>>(feats, idx, out, nquad, PPS);
        }
    } else {
        int n4 = out_size / 4;
        {
            int blocks = min((n4 + 255) / 256, 4096);
            zero_out_kernel<<<blocks, 256, 0, stream>>>(out, n4);
        }
        {
            int pillars_per_block = 256 / 64;
            int blocks = (P + pillars_per_block - 1) / pillars_per_block;
            direct_scatter_kernel<<<blocks, 256, 0, stream>>>(feats, coords, out, P);
        }
    }
}